// Round 10
// baseline (3834.641 us; speedup 1.0000x reference)
//
#include <hip/hip_runtime.h>
#include <hip/hip_bf16.h>
#include <math.h>

#define L_IN 1549
#define S_OUT 512

typedef __hip_bfloat16 bf16;
typedef __attribute__((ext_vector_type(8))) short bfrag;    // 8 bf16 (4 VGPRs)
typedef __attribute__((ext_vector_type(4))) float f32x4;    // MFMA accumulator

__device__ __forceinline__ float bfbits2f(unsigned short u) {
    union { unsigned int i; float f; } x;
    x.i = ((unsigned int)u) << 16;
    return x.f;
}
__device__ __forceinline__ unsigned short f2bfbits(float f) {
    union { float f; unsigned int i; } x; x.f = f;
    unsigned int lsb = (x.i >> 16) & 1;
    return (unsigned short)((x.i + 0x7fff + lsb) >> 16);
}
// 8 fp32 -> 8 bf16 packed in a float4 (RNE)
__device__ __forceinline__ float4 cv8(const float* p) {
    float4 u0 = *(const float4*)p;
    float4 u1 = *(const float4*)(p + 4);
    union { float4 f; unsigned short h[8]; } o;
    o.h[0] = f2bfbits(u0.x); o.h[1] = f2bfbits(u0.y);
    o.h[2] = f2bfbits(u0.z); o.h[3] = f2bfbits(u0.w);
    o.h[4] = f2bfbits(u1.x); o.h[5] = f2bfbits(u1.y);
    o.h[6] = f2bfbits(u1.z); o.h[7] = f2bfbits(u1.w);
    return o.f;
}

// bf16-pair dot product: c + lo(w)*lo(h) + hi(w)*hi(h)
#if __has_builtin(__builtin_amdgcn_fdot2_f32_bf16)
typedef __attribute__((ext_vector_type(2))) __bf16 v2bf;
__device__ __forceinline__ float dot2bf(unsigned int w, unsigned int h, float c) {
    union { unsigned int u; v2bf v; } a, b;
    a.u = w; b.u = h;
    return __builtin_amdgcn_fdot2_f32_bf16(a.v, b.v, c, false);
}
#else
__device__ __forceinline__ float dot2bf(unsigned int w, unsigned int h, float c) {
    union { unsigned int i; float f; } w0, w1, h0, h1;
    w0.i = w << 16; w1.i = w & 0xffff0000u;
    h0.i = h << 16; h1.i = h & 0xffff0000u;
    return c + w0.f * h0.f + w1.f * h1.f;
}
#endif

// ---------------------------------------------------------------------------
// conv1d(k=16,pad=1) + BN + ReLU + maxpool(3,3) + transpose -> h0 (B,512,32) bf16
// ---------------------------------------------------------------------------
__global__ __launch_bounds__(256) void conv_bn_pool(
    const float* __restrict__ x, const float* __restrict__ w,
    const float* __restrict__ cb, const float* __restrict__ gamma,
    const float* __restrict__ beta, const float* __restrict__ mean,
    const float* __restrict__ var, bf16* __restrict__ h0)
{
    int b  = blockIdx.y;
    int sg = blockIdx.x;
    __shared__ float xs[32][40];
    int tid = threadIdx.x;
    int base = sg * 24;
    for (int i = tid; i < 32 * 40; i += 256) {
        int ci = i / 40, dl = i % 40;
        int l = base - 1 + dl;
        xs[ci][dl] = (l >= 0 && l < L_IN) ? x[(size_t)(b * 32 + ci) * L_IN + l] : 0.f;
    }
    __syncthreads();
    int c = tid & 31, sl = tid >> 5;
    float scale = gamma[c] * rsqrtf(var[c] + 1e-5f);
    float shift = beta[c] - mean[c] * scale;
    float bias = cb[c];
    float best = -1e30f;
    #pragma unroll
    for (int p = 0; p < 3; ++p) {
        float acc = bias;
        for (int ci = 0; ci < 32; ++ci) {
            const float* wr = w + (size_t)(c * 32 + ci) * 16;
            int off = 3 * sl + p;
            #pragma unroll
            for (int kk = 0; kk < 16; ++kk) acc += xs[ci][off + kk] * wr[kk];
        }
        float y = acc * scale + shift;
        y = fmaxf(y, 0.f);
        best = fmaxf(best, y);
    }
    int s = sg * 8 + sl;
    h0[((size_t)b * S_OUT + s) * 32 + c] = __float2bfloat16(best);
}

// ---------------------------------------------------------------------------
// Pack 4 x W_hh (1024,256) fp32 for lstm_reg in ONE launch (blockIdx.y = set).
// v4 column map: thread t owns gate cols 2t, 2t+1; g = 2t+col.
//  R (reg,   kp   0..99):  i = kp*1024 + col*512 + t
//  L (LDS,   kp 100..113): i = 102400 + (kp-100)*1024 + 2t+col
//  S (reg2,  kp 114..127): i = 116736 + (kp-114)*1024 + 2t+col
// ---------------------------------------------------------------------------
__global__ void pack_lstm4(
    const float* __restrict__ W0, const float* __restrict__ W1,
    const float* __restrict__ W2, const float* __restrict__ W3,
    unsigned int* __restrict__ outbase)
{
    int set = blockIdx.y;
    const float* W = (set == 0) ? W0 : (set == 1) ? W1 : (set == 2) ? W2 : W3;
    unsigned int* out = outbase + (size_t)set * 131072;
    int i = blockIdx.x * 256 + threadIdx.x;   // 0..131071
    int kp, t, col;
    if (i < 102400) {
        kp = i >> 10; col = (i >> 9) & 1; t = i & 511;
    } else if (i < 116736) {
        int j = i - 102400;
        kp = 100 + (j >> 10); t = (j & 1023) >> 1; col = j & 1;
    } else {
        int j = i - 116736;
        kp = 114 + (j >> 10); t = (j & 1023) >> 1; col = j & 1;
    }
    int g = 2 * t + col;
    unsigned int lo = f2bfbits(W[(size_t)g * 256 + 2 * kp]);
    unsigned int hi = f2bfbits(W[(size_t)g * 256 + 2 * kp + 1]);
    out[i] = lo | (hi << 16);
}

// ---------------------------------------------------------------------------
// MFMA bf16 GEMM:  C = A @ B^T + bias.  A (M,K) bf16, B (N,K) fp32 (converted
// to bf16 during staging).  128x128 tile, BK=32, 4 waves x 4x4 16x16x32 MFMAs.
// ---------------------------------------------------------------------------
__global__ __launch_bounds__(256) void gemm_mfma(
    const bf16* __restrict__ A,
    const float* __restrict__ Bm0, const float* __restrict__ Bm1, const float* __restrict__ Bm2,
    const float* __restrict__ bs0, const float* __restrict__ bs1, const float* __restrict__ bs2,
    bf16* __restrict__ Cm0, bf16* __restrict__ Cm1, bf16* __restrict__ Cm2,
    int M, int N, int K)
{
    int z = blockIdx.z;
    const float* B = (z == 0) ? Bm0 : ((z == 1) ? Bm1 : Bm2);
    const float* bias = (z == 0) ? bs0 : ((z == 1) ? bs1 : bs2);
    bf16* C = (z == 0) ? Cm0 : ((z == 1) ? Cm1 : Cm2);

    __shared__ bf16 As[128 * 32];
    __shared__ bf16 Bs[128 * 32];

    int tid = threadIdx.x;
    int lane = tid & 63;
    int wave = tid >> 6;
    int bm = blockIdx.y, bn = blockIdx.x;
    int wm = (wave >> 1) * 64;
    int wn = (wave & 1) * 64;

    int sr = tid >> 2;
    int sc = (tid & 3) * 8;
    const bf16* Ag = A + (size_t)(bm * 128 + sr) * K + sc;
    const float* Bg = B + (size_t)(bn * 128 + sr) * K + sc;

    int fm = lane & 15;
    int fk = (lane >> 4) * 8;

    f32x4 acc[4][4];
    #pragma unroll
    for (int i = 0; i < 4; ++i)
        #pragma unroll
        for (int j = 0; j < 4; ++j) acc[i][j] = (f32x4)(0.f);

    for (int k0 = 0; k0 < K; k0 += 32) {
        float4 a0 = *(const float4*)(Ag + k0);
        float4 a1 = *(const float4*)(Ag + (size_t)64 * K + k0);
        float4 b0 = cv8(Bg + k0);
        float4 b1 = cv8(Bg + (size_t)64 * K + k0);
        __syncthreads();
        *(float4*)(As + sr * 32 + sc)        = a0;
        *(float4*)(As + (sr + 64) * 32 + sc) = a1;
        *(float4*)(Bs + sr * 32 + sc)        = b0;
        *(float4*)(Bs + (sr + 64) * 32 + sc) = b1;
        __syncthreads();

        bfrag af[4], bfr[4];
        #pragma unroll
        for (int i = 0; i < 4; ++i)
            af[i] = *(const bfrag*)(As + (wm + i * 16 + fm) * 32 + fk);
        #pragma unroll
        for (int j = 0; j < 4; ++j)
            bfr[j] = *(const bfrag*)(Bs + (wn + j * 16 + fm) * 32 + fk);
        #pragma unroll
        for (int i = 0; i < 4; ++i)
            #pragma unroll
            for (int j = 0; j < 4; ++j)
                acc[i][j] = __builtin_amdgcn_mfma_f32_16x16x32_bf16(
                    af[i], bfr[j], acc[i][j], 0, 0, 0);
    }

    int rbase = (lane >> 4) * 4;
    #pragma unroll
    for (int j = 0; j < 4; ++j) {
        int n = bn * 128 + wn + j * 16 + (lane & 15);
        float bv = bias[n];
        #pragma unroll
        for (int i = 0; i < 4; ++i) {
            #pragma unroll
            for (int r = 0; r < 4; ++r) {
                int m = bm * 128 + wm + i * 16 + rbase + r;
                C[(size_t)m * N + n] = __float2bfloat16(acc[i][j][r] + bv);
            }
        }
    }
}

// ---------------------------------------------------------------------------
// LSTM recurrence v7: ALL weights on-chip persistent.
// One block per (batch,dir), 512 thr.  Thread t owns gate cols (2t,2t+1):
//   kp 0..99   -> wr[200] registers
//   kp 100..113 -> LDS (56 KB, staged once)
//   kp 114..127 -> wr2[14] uint2 registers (hoisted: data is step-invariant)
// 4 accumulation chains per thread (even/odd kp) for dot2-latency cover.
// h double-buffered in LDS; 2 barriers/step; out store post-barrier.
// ---------------------------------------------------------------------------
__global__ __launch_bounds__(512, 2) void lstm_reg(
    const bf16* __restrict__ xg_f, const bf16* __restrict__ xg_b,
    const unsigned int* __restrict__ Wl, bf16* __restrict__ out)
{
    int u = blockIdx.x;          // 0..127
    int b = u & 63, dir = u >> 6;
    const unsigned int* W = Wl + (size_t)dir * 131072;
    const bf16* xg = dir ? xg_b : xg_f;
    int t = threadIdx.x;         // 0..511

    __shared__ unsigned int lw[14336];                    // 56 KB weight slice
    __shared__ __align__(16) unsigned int hsb[2][128];    // h bf16 pairs, dbuf
    __shared__ float gsh[1024];                           // gates

    unsigned int wr[200];
    #pragma unroll
    for (int j = 0; j < 200; ++j) wr[j] = W[j * 512 + t];
    uint2 wr2[14];
    #pragma unroll
    for (int s = 0; s < 14; ++s)
        wr2[s] = *(const uint2*)(W + 116736 + s * 1024 + 2 * t);
    for (int i = t; i < 14336; i += 512) lw[i] = W[102400 + i];
    if (t < 128) { hsb[0][t] = 0u; }
    float cst = 0.f;             // cell state of position t (t < 256)
    __syncthreads();

    int par = 0;
    unsigned short hb = 0;
    size_t oaddr = 0;
    bool have_out = false;

    for (int step = 0; step < 512; ++step) {
        int ts = dir ? (511 - step) : step;

        unsigned int xv =
            *(const unsigned int*)(xg + ((size_t)b * 512 + ts) * 1024 + 2 * t);

        const unsigned int* hs = hsb[par];
        float a0e = 0.f, a0o = 0.f, a1e = 0.f, a1o = 0.f;
        #pragma unroll
        for (int q = 0; q < 32; ++q) {
            uint4 hv = *(const uint4*)&hs[q * 4];
            #pragma unroll
            for (int r = 0; r < 4; ++r) {
                int kp = q * 4 + r;
                unsigned int h2 = (&hv.x)[r];
                unsigned int w0, w1;
                if (kp < 100) {
                    w0 = wr[kp * 2]; w1 = wr[kp * 2 + 1];
                } else if (kp < 114) {
                    uint2 wv = *(const uint2*)&lw[(kp - 100) * 1024 + 2 * t];
                    w0 = wv.x; w1 = wv.y;
                } else {
                    w0 = wr2[kp - 114].x; w1 = wr2[kp - 114].y;
                }
                if (r & 1) {
                    a0o = dot2bf(w0, h2, a0o);
                    a1o = dot2bf(w1, h2, a1o);
                } else {
                    a0e = dot2bf(w0, h2, a0e);
                    a1e = dot2bf(w1, h2, a1e);
                }
            }
        }
        float a0 = (a0e + a0o) + bfbits2f((unsigned short)(xv & 0xffff));
        float a1 = (a1e + a1o) + bfbits2f((unsigned short)(xv >> 16));

        *(float2*)&gsh[2 * t] = make_float2(a0, a1);
        __syncthreads();

        if (t < 256) {
            float gi = gsh[t], gf = gsh[256 + t], gg = gsh[512 + t], go = gsh[768 + t];
            float si = 1.f / (1.f + expf(-gi));
            float sf = 1.f / (1.f + expf(-gf));
            float so = 1.f / (1.f + expf(-go));
            cst = sf * cst + si * tanhf(gg);
            float h = so * tanhf(cst);
            hb = f2bfbits(h);
            ((unsigned short*)hsb[par ^ 1])[t] = hb;
            oaddr = ((size_t)b * 512 + ts) * 512 + dir * 256 + t;
            have_out = true;
        }
        __syncthreads();
        // out store off the critical path: drains at the NEXT step's barrier
        if (have_out) {
            *(unsigned short*)(out + oaddr) = hb;
            have_out = false;
        }
        par ^= 1;
    }
}

// ---------------------------------------------------------------------------
// V transpose: vt[b][n][s] = v[b][s][n]   (64x64 tiles via LDS)
// ---------------------------------------------------------------------------
__global__ __launch_bounds__(256) void vt_transpose(
    const bf16* __restrict__ v, bf16* __restrict__ vt)
{
    __shared__ unsigned short tile[64 * 73];
    int b = blockIdx.z;
    int s0 = blockIdx.x * 64, n0 = blockIdx.y * 64;
    int tid = threadIdx.x;
    #pragma unroll
    for (int u = 0; u < 2; ++u) {
        int idx = tid + u * 256;
        int si = idx >> 3, nj = (idx & 7) << 3;
        bfrag val = *(const bfrag*)(v + ((size_t)(b * 512 + s0 + si)) * 512 + n0 + nj);
        #pragma unroll
        for (int jj = 0; jj < 8; ++jj)
            tile[(nj + jj) * 73 + si] = ((unsigned short*)&val)[jj];
    }
    __syncthreads();
    #pragma unroll
    for (int u = 0; u < 2; ++u) {
        int idx = tid + u * 256;
        int ni = idx >> 3, sj = (idx & 7) << 3;
        unsigned short outv[8];
        #pragma unroll
        for (int jj = 0; jj < 8; ++jj)
            outv[jj] = tile[ni * 73 + sj + jj];
        *(float4*)(vt + (size_t)b * 262144 + (size_t)(n0 + ni) * 512 + s0 + sj) =
            *(float4*)outv;
    }
}

// ---------------------------------------------------------------------------
// MFMA attention (unchanged from round 7).
// ---------------------------------------------------------------------------
__global__ __launch_bounds__(256, 2) void attention_mfma(
    const bf16* __restrict__ q, const bf16* __restrict__ k,
    const bf16* __restrict__ vt, bf16* r)
{
    int b = blockIdx.y;
    int s0 = blockIdx.x * 32;
    int tid = threadIdx.x;
    int wave = tid >> 6;
    int sw = wave & 1, dh = wave >> 1;
    int lane = tid & 63;
    int L15 = lane & 15, quad = lane >> 4;

    const bf16* qrow = q + ((size_t)(b * 512 + s0 + sw * 16 + L15)) * 512;
    bfrag qf[8][2];
    #pragma unroll
    for (int h = 0; h < 8; ++h) {
        qf[h][0] = *(const bfrag*)(qrow + h * 64 + quad * 8);
        qf[h][1] = *(const bfrag*)(qrow + h * 64 + 32 + quad * 8);
    }

    f32x4 ctxa[8][2];
    #pragma unroll
    for (int h = 0; h < 8; ++h) {
        ctxa[h][0] = (f32x4)(0.f);
        ctxa[h][1] = (f32x4)(0.f);
    }

    int tperm = ((L15 >> 2) << 3) + (L15 & 3);
    const bf16* kbase = k + (size_t)(b * 512) * 512;
    const bf16* vbase = vt + (size_t)b * 262144;

    for (int tc = 0; tc < 512; tc += 32) {
        f32x4 sa[8][2];
        #pragma unroll
        for (int h = 0; h < 8; ++h) {
            #pragma unroll
            for (int tile = 0; tile < 2; ++tile) {
                const bf16* krow = kbase
                    + (size_t)(tc + tile * 4 + tperm) * 512 + h * 64 + quad * 8;
                bfrag a0 = *(const bfrag*)(krow);
                bfrag a1 = *(const bfrag*)(krow + 32);
                f32x4 acc = __builtin_amdgcn_mfma_f32_16x16x32_bf16(
                    a0, qf[h][0], (f32x4)(0.f), 0, 0, 0);
                acc = __builtin_amdgcn_mfma_f32_16x16x32_bf16(
                    a1, qf[h][1], acc, 0, 0, 0);
                sa[h][tile] = acc;
            }
        }
        bfrag pf[8];
        #pragma unroll
        for (int tile = 0; tile < 2; ++tile) {
            #pragma unroll
            for (int rr = 0; rr < 4; ++rr) {
                float sc[8];
                float m = -1e30f;
                #pragma unroll
                for (int h = 0; h < 8; ++h) {
                    sc[h] = sa[h][tile][rr] * 0.125f;
                    m = fmaxf(m, sc[h]);
                }
                float sum = 0.f;
                #pragma unroll
                for (int h = 0; h < 8; ++h) sum += expf(sc[h] - m);
                float lse = m + logf(sum);
                #pragma unroll
                for (int h = 0; h < 8; ++h)
                    ((unsigned short*)&pf[h])[tile * 4 + rr] = f2bfbits(sc[h] - lse);
            }
        }
        #pragma unroll
        for (int h = 0; h < 8; ++h) {
            #pragma unroll
            for (int dt = 0; dt < 2; ++dt) {
                int n = h * 64 + dh * 32 + dt * 16 + L15;
                bfrag vf = *(const bfrag*)(vbase + (size_t)n * 512 + tc + quad * 8);
                ctxa[h][dt] = __builtin_amdgcn_mfma_f32_16x16x32_bf16(
                    pf[h], vf, ctxa[h][dt], 0, 0, 0);
            }
        }
    }
    #pragma unroll
    for (int h = 0; h < 8; ++h) {
        #pragma unroll
        for (int dt = 0; dt < 2; ++dt) {
            int n = h * 64 + dh * 32 + dt * 16 + L15;
            #pragma unroll
            for (int rr = 0; rr < 4; ++rr) {
                size_t addr =
                    ((size_t)(b * 512 + s0 + sw * 16 + quad * 4 + rr)) * 512 + n;
                float o = __bfloat162float(r[addr]);
                r[addr] = __float2bfloat16(o + ctxa[h][dt][rr]);
            }
        }
    }
}

// ---------------------------------------------------------------------------
// LayerNorm(last dim) -> mean over S -> fc.  One block per (b, s) row.
// ---------------------------------------------------------------------------
__device__ __forceinline__ float block_sum(float val, float* red, int tid)
{
    #pragma unroll
    for (int o = 32; o > 0; o >>= 1) val += __shfl_down(val, o);
    __syncthreads();
    if ((tid & 63) == 0) red[tid >> 6] = val;
    __syncthreads();
    return red[0] + red[1] + red[2] + red[3];
}

__global__ __launch_bounds__(256) void ln_pool_fc(
    const bf16* __restrict__ r, const float* __restrict__ g, const float* __restrict__ bt,
    const float* __restrict__ fcw, const float* __restrict__ fcb, float* __restrict__ out)
{
    __shared__ float red[4];
    int b = blockIdx.y, s = blockIdx.x, tid = threadIdx.x;
    const bf16* row = r + ((size_t)(b * 512 + s)) * 512;
    __hip_bfloat162 rv = *(const __hip_bfloat162*)(row + tid * 2);
    float v0 = __bfloat162float(rv.x), v1 = __bfloat162float(rv.y);
    float tot = block_sum(v0 + v1, red, tid);
    float mu = tot * (1.f / 512.f);
    float d0 = v0 - mu, d1 = v1 - mu;
    float sq = block_sum(d0 * d0 + d1 * d1, red, tid);
    float rs = rsqrtf(sq * (1.f / 512.f) + 1e-5f);
    int n0 = tid * 2;
    float term = d0 * rs * g[n0] * fcw[n0] + d1 * rs * g[n0 + 1] * fcw[n0 + 1];
    if (s == 0) term += 512.f * (bt[n0] * fcw[n0] + bt[n0 + 1] * fcw[n0 + 1]);
    float D = block_sum(term, red, tid);
    if (tid == 0) {
        float val = D * (1.f / 512.f);
        if (s == 0) val += fcb[0];
        atomicAdd(out + b, val);
    }
}

// ---------------------------------------------------------------------------
// Workspace layout (< 200 MiB):
//   [0,64M)        xgf bf16            -> later q,k
//   [64,128M)      xgb bf16            -> later v
//   [128,160M)     out0 bf16           -> later vt (V transposed)
//   [160,192M)     out1 bf16 (attention in-place)
//   [192,194M)     h0 bf16
//   [194,196M)     wl0/wl1 (4 contiguous sets x 131,072 dwords)
// ---------------------------------------------------------------------------
extern "C" void kernel_launch(void* const* d_in, const int* in_sizes, int n_in,
                              void* d_out, int out_size, void* d_ws, size_t ws_size,
                              hipStream_t stream)
{
    (void)in_sizes; (void)n_in; (void)ws_size;
    const float* x      = (const float*)d_in[0];
    const float* conv_w = (const float*)d_in[1];
    const float* conv_b = (const float*)d_in[2];
    const float* bn_g   = (const float*)d_in[3];
    const float* bn_b   = (const float*)d_in[4];
    const float* bn_m   = (const float*)d_in[5];
    const float* bn_v   = (const float*)d_in[6];
    const float* W_ih0f = (const float*)d_in[7];
    const float* W_hh0f = (const float*)d_in[8];
    const float* b0f    = (const float*)d_in[9];
    const float* W_ih0b = (const float*)d_in[10];
    const float* W_hh0b = (const float*)d_in[11];
    const float* b0b    = (const float*)d_in[12];
    const float* W_ih1f = (const float*)d_in[13];
    const float* W_hh1f = (const float*)d_in[14];
    const float* b1f    = (const float*)d_in[15];
    const float* W_ih1b = (const float*)d_in[16];
    const float* W_hh1b = (const float*)d_in[17];
    const float* b1b    = (const float*)d_in[18];
    const float* Wq = (const float*)d_in[19];
    const float* bq = (const float*)d_in[20];
    const float* Wk = (const float*)d_in[21];
    const float* bk = (const float*)d_in[22];
    const float* Wv = (const float*)d_in[23];
    const float* bv = (const float*)d_in[24];
    const float* ln_g = (const float*)d_in[25];
    const float* ln_b = (const float*)d_in[26];
    const float* fc_w = (const float*)d_in[27];
    const float* fc_b = (const float*)d_in[28];
    float* out = (float*)d_out;

    char* ws = (char*)d_ws;
    bf16* xgf  = (bf16*)ws;                               // 33,554,432
    bf16* xgb  = xgf + 33554432;                          // 33,554,432
    bf16* out0 = (bf16*)(ws + 134217728);                 // 16,777,216
    bf16* out1 = (bf16*)(ws + 167772160);                 // 16,777,216
    bf16* h0   = (bf16*)(ws + 201326592);                 // 1,048,576
    unsigned int* wl0 = (unsigned int*)(ws + 203423744);  // 262,144 dwords
    unsigned int* wl1 = wl0 + 262144;                     // 262,144 dwords
    // q,k,v alias the (dead after lstm1) xg region; vt aliases dead out0
    bf16* qb = xgf;
    bf16* kb = xgf + 16777216;
    bf16* vb = xgb;
    bf16* vtb = out0;

    hipMemsetAsync(d_out, 0, (size_t)out_size * sizeof(float), stream);

    pack_lstm4<<<dim3(512, 4), 256, 0, stream>>>(
        W_hh0f, W_hh0b, W_hh1f, W_hh1b, wl0);

    conv_bn_pool<<<dim3(64, 64), 256, 0, stream>>>(
        x, conv_w, conv_b, bn_g, bn_b, bn_m, bn_v, h0);

    // layer-0 input projections (K=32), fwd+bwd in one launch
    gemm_mfma<<<dim3(8, 256, 2), 256, 0, stream>>>(
        h0, W_ih0f, W_ih0b, nullptr, b0f, b0b, nullptr, xgf, xgb, nullptr,
        32768, 1024, 32);

    lstm_reg<<<128, 512, 0, stream>>>(xgf, xgb, wl0, out0);

    // layer-1 input projections (K=512)
    gemm_mfma<<<dim3(8, 256, 2), 256, 0, stream>>>(
        out0, W_ih1f, W_ih1b, nullptr, b1f, b1b, nullptr, xgf, xgb, nullptr,
        32768, 1024, 512);

    lstm_reg<<<128, 512, 0, stream>>>(xgf, xgb, wl1, out1);

    // QKV projections (N=512), 3-way
    gemm_mfma<<<dim3(4, 256, 3), 256, 0, stream>>>(
        out1, Wq, Wk, Wv, bq, bk, bv, qb, kb, vb,
        32768, 512, 512);

    vt_transpose<<<dim3(8, 8, 64), 256, 0, stream>>>(vb, vtb);

    attention_mfma<<<dim3(16, 64), 256, 0, stream>>>(qb, kb, vtb, out1);

    ln_pool_fc<<<dim3(512, 64), 256, 0, stream>>>(out1, ln_g, ln_b, fc_w, fc_b, out);
}

// Round 11
// 3626.998 us; speedup vs baseline: 1.0572x; 1.0572x over previous
//
#include <hip/hip_runtime.h>
#include <hip/hip_bf16.h>
#include <math.h>

#define L_IN 1549
#define S_OUT 512

typedef __hip_bfloat16 bf16;
typedef __attribute__((ext_vector_type(8))) short bfrag;    // 8 bf16 (4 VGPRs)
typedef __attribute__((ext_vector_type(4))) float f32x4;    // MFMA accumulator

__device__ __forceinline__ float bfbits2f(unsigned short u) {
    union { unsigned int i; float f; } x;
    x.i = ((unsigned int)u) << 16;
    return x.f;
}
__device__ __forceinline__ unsigned short f2bfbits(float f) {
    union { float f; unsigned int i; } x; x.f = f;
    unsigned int lsb = (x.i >> 16) & 1;
    return (unsigned short)((x.i + 0x7fff + lsb) >> 16);
}
// 8 fp32 -> 8 bf16 packed in a float4 (RNE)
__device__ __forceinline__ float4 cv8(const float* p) {
    float4 u0 = *(const float4*)p;
    float4 u1 = *(const float4*)(p + 4);
    union { float4 f; unsigned short h[8]; } o;
    o.h[0] = f2bfbits(u0.x); o.h[1] = f2bfbits(u0.y);
    o.h[2] = f2bfbits(u0.z); o.h[3] = f2bfbits(u0.w);
    o.h[4] = f2bfbits(u1.x); o.h[5] = f2bfbits(u1.y);
    o.h[6] = f2bfbits(u1.z); o.h[7] = f2bfbits(u1.w);
    return o.f;
}

// bf16-pair dot product: c + lo(w)*lo(h) + hi(w)*hi(h)
#if __has_builtin(__builtin_amdgcn_fdot2_f32_bf16)
typedef __attribute__((ext_vector_type(2))) __bf16 v2bf;
__device__ __forceinline__ float dot2bf(unsigned int w, unsigned int h, float c) {
    union { unsigned int u; v2bf v; } a, b;
    a.u = w; b.u = h;
    return __builtin_amdgcn_fdot2_f32_bf16(a.v, b.v, c, false);
}
#else
__device__ __forceinline__ float dot2bf(unsigned int w, unsigned int h, float c) {
    union { unsigned int i; float f; } w0, w1, h0, h1;
    w0.i = w << 16; w1.i = w & 0xffff0000u;
    h0.i = h << 16; h1.i = h & 0xffff0000u;
    return c + w0.f * h0.f + w1.f * h1.f;
}
#endif

// ---------------------------------------------------------------------------
// conv1d(k=16,pad=1) + BN + ReLU + maxpool(3,3) + transpose -> h0 (B,512,32) bf16
// ---------------------------------------------------------------------------
__global__ __launch_bounds__(256) void conv_bn_pool(
    const float* __restrict__ x, const float* __restrict__ w,
    const float* __restrict__ cb, const float* __restrict__ gamma,
    const float* __restrict__ beta, const float* __restrict__ mean,
    const float* __restrict__ var, bf16* __restrict__ h0)
{
    int b  = blockIdx.y;
    int sg = blockIdx.x;
    __shared__ float xs[32][40];
    int tid = threadIdx.x;
    int base = sg * 24;
    for (int i = tid; i < 32 * 40; i += 256) {
        int ci = i / 40, dl = i % 40;
        int l = base - 1 + dl;
        xs[ci][dl] = (l >= 0 && l < L_IN) ? x[(size_t)(b * 32 + ci) * L_IN + l] : 0.f;
    }
    __syncthreads();
    int c = tid & 31, sl = tid >> 5;
    float scale = gamma[c] * rsqrtf(var[c] + 1e-5f);
    float shift = beta[c] - mean[c] * scale;
    float bias = cb[c];
    float best = -1e30f;
    #pragma unroll
    for (int p = 0; p < 3; ++p) {
        float acc = bias;
        for (int ci = 0; ci < 32; ++ci) {
            const float* wr = w + (size_t)(c * 32 + ci) * 16;
            int off = 3 * sl + p;
            #pragma unroll
            for (int kk = 0; kk < 16; ++kk) acc += xs[ci][off + kk] * wr[kk];
        }
        float y = acc * scale + shift;
        y = fmaxf(y, 0.f);
        best = fmaxf(best, y);
    }
    int s = sg * 8 + sl;
    h0[((size_t)b * S_OUT + s) * 32 + c] = __float2bfloat16(best);
}

// ---------------------------------------------------------------------------
// Pack 4 x W_hh (1024,256) fp32 for lstm_reg in ONE launch (blockIdx.y = set).
// v4 column map: thread t owns gate cols 2t, 2t+1; g = 2t+col.
//  R (reg,   kp   0..99):  i = kp*1024 + col*512 + t
//  L (LDS,   kp 100..113): i = 102400 + (kp-100)*1024 + 2t+col
//  S (stream,kp 114..127): i = 116736 + (kp-114)*1024 + 2t+col
// ---------------------------------------------------------------------------
__global__ void pack_lstm4(
    const float* __restrict__ W0, const float* __restrict__ W1,
    const float* __restrict__ W2, const float* __restrict__ W3,
    unsigned int* __restrict__ outbase)
{
    int set = blockIdx.y;
    const float* W = (set == 0) ? W0 : (set == 1) ? W1 : (set == 2) ? W2 : W3;
    unsigned int* out = outbase + (size_t)set * 131072;
    int i = blockIdx.x * 256 + threadIdx.x;   // 0..131071
    int kp, t, col;
    if (i < 102400) {
        kp = i >> 10; col = (i >> 9) & 1; t = i & 511;
    } else if (i < 116736) {
        int j = i - 102400;
        kp = 100 + (j >> 10); t = (j & 1023) >> 1; col = j & 1;
    } else {
        int j = i - 116736;
        kp = 114 + (j >> 10); t = (j & 1023) >> 1; col = j & 1;
    }
    int g = 2 * t + col;
    unsigned int lo = f2bfbits(W[(size_t)g * 256 + 2 * kp]);
    unsigned int hi = f2bfbits(W[(size_t)g * 256 + 2 * kp + 1]);
    out[i] = lo | (hi << 16);
}

// ---------------------------------------------------------------------------
// MFMA bf16 GEMM:  C = A @ B^T + bias.  A (M,K) bf16, B (N,K) fp32 (converted
// to bf16 during staging).  128x128 tile, BK=32, 4 waves x 4x4 16x16x32 MFMAs.
// ---------------------------------------------------------------------------
__global__ __launch_bounds__(256) void gemm_mfma(
    const bf16* __restrict__ A,
    const float* __restrict__ Bm0, const float* __restrict__ Bm1, const float* __restrict__ Bm2,
    const float* __restrict__ bs0, const float* __restrict__ bs1, const float* __restrict__ bs2,
    bf16* __restrict__ Cm0, bf16* __restrict__ Cm1, bf16* __restrict__ Cm2,
    int M, int N, int K)
{
    int z = blockIdx.z;
    const float* B = (z == 0) ? Bm0 : ((z == 1) ? Bm1 : Bm2);
    const float* bias = (z == 0) ? bs0 : ((z == 1) ? bs1 : bs2);
    bf16* C = (z == 0) ? Cm0 : ((z == 1) ? Cm1 : Cm2);

    __shared__ bf16 As[128 * 32];
    __shared__ bf16 Bs[128 * 32];

    int tid = threadIdx.x;
    int lane = tid & 63;
    int wave = tid >> 6;
    int bm = blockIdx.y, bn = blockIdx.x;
    int wm = (wave >> 1) * 64;
    int wn = (wave & 1) * 64;

    int sr = tid >> 2;
    int sc = (tid & 3) * 8;
    const bf16* Ag = A + (size_t)(bm * 128 + sr) * K + sc;
    const float* Bg = B + (size_t)(bn * 128 + sr) * K + sc;

    int fm = lane & 15;
    int fk = (lane >> 4) * 8;

    f32x4 acc[4][4];
    #pragma unroll
    for (int i = 0; i < 4; ++i)
        #pragma unroll
        for (int j = 0; j < 4; ++j) acc[i][j] = (f32x4)(0.f);

    for (int k0 = 0; k0 < K; k0 += 32) {
        float4 a0 = *(const float4*)(Ag + k0);
        float4 a1 = *(const float4*)(Ag + (size_t)64 * K + k0);
        float4 b0 = cv8(Bg + k0);
        float4 b1 = cv8(Bg + (size_t)64 * K + k0);
        __syncthreads();
        *(float4*)(As + sr * 32 + sc)        = a0;
        *(float4*)(As + (sr + 64) * 32 + sc) = a1;
        *(float4*)(Bs + sr * 32 + sc)        = b0;
        *(float4*)(Bs + (sr + 64) * 32 + sc) = b1;
        __syncthreads();

        bfrag af[4], bfr[4];
        #pragma unroll
        for (int i = 0; i < 4; ++i)
            af[i] = *(const bfrag*)(As + (wm + i * 16 + fm) * 32 + fk);
        #pragma unroll
        for (int j = 0; j < 4; ++j)
            bfr[j] = *(const bfrag*)(Bs + (wn + j * 16 + fm) * 32 + fk);
        #pragma unroll
        for (int i = 0; i < 4; ++i)
            #pragma unroll
            for (int j = 0; j < 4; ++j)
                acc[i][j] = __builtin_amdgcn_mfma_f32_16x16x32_bf16(
                    af[i], bfr[j], acc[i][j], 0, 0, 0);
    }

    int rbase = (lane >> 4) * 4;
    #pragma unroll
    for (int j = 0; j < 4; ++j) {
        int n = bn * 128 + wn + j * 16 + (lane & 15);
        float bv = bias[n];
        #pragma unroll
        for (int i = 0; i < 4; ++i) {
            #pragma unroll
            for (int r = 0; r < 4; ++r) {
                int m = bm * 128 + wm + i * 16 + rbase + r;
                C[(size_t)m * N + n] = __float2bfloat16(acc[i][j][r] + bv);
            }
        }
    }
}

// ---------------------------------------------------------------------------
// LSTM recurrence (round-9 verified best: 978 us/layer).
// One block per (batch,dir), 512 thr.  Thread t owns gate cols (2t,2t+1),
// kp 0..99 in registers, 100..113 in LDS, 114..127 streamed from L2 each
// step (streamed-not-hoisted: AGPR-parked weights cost a VALU read per use,
// measured slower in R10; L2 stream loads overlap the dot phase).
// h double-buffered in LDS; 2 barriers/step; out store post-barrier.
// ---------------------------------------------------------------------------
__global__ __launch_bounds__(512, 2) void lstm_reg(
    const bf16* __restrict__ xg_f, const bf16* __restrict__ xg_b,
    const unsigned int* __restrict__ Wl, bf16* __restrict__ out)
{
    int u = blockIdx.x;          // 0..127
    int b = u & 63, dir = u >> 6;
    const unsigned int* W = Wl + (size_t)dir * 131072;
    const bf16* xg = dir ? xg_b : xg_f;
    int t = threadIdx.x;         // 0..511

    __shared__ unsigned int lw[14336];                    // 56 KB weight slice
    __shared__ __align__(16) unsigned int hsb[2][128];    // h bf16 pairs, dbuf
    __shared__ float gsh[1024];                           // gates

    unsigned int wr[200];
    #pragma unroll
    for (int j = 0; j < 200; ++j) wr[j] = W[j * 512 + t];
    for (int i = t; i < 14336; i += 512) lw[i] = W[102400 + i];
    if (t < 128) { hsb[0][t] = 0u; }
    float cst = 0.f;             // cell state of position t (t < 256)
    __syncthreads();

    const unsigned int* Wst = W + 116736;
    int par = 0;
    unsigned short hb = 0;
    size_t oaddr = 0;
    bool have_out = false;

    for (int step = 0; step < 512; ++step) {
        int ts = dir ? (511 - step) : step;

        // issue stream + xg loads first (latency overlapped with reg MACs)
        uint2 sw[14];
        #pragma unroll
        for (int s = 0; s < 14; ++s)
            sw[s] = *(const uint2*)(Wst + s * 1024 + 2 * t);
        unsigned int xv =
            *(const unsigned int*)(xg + ((size_t)b * 512 + ts) * 1024 + 2 * t);

        const unsigned int* hs = hsb[par];
        float a0 = 0.f, a1 = 0.f;
        #pragma unroll
        for (int q = 0; q < 32; ++q) {
            uint4 hv = *(const uint4*)&hs[q * 4];
            #pragma unroll
            for (int r = 0; r < 4; ++r) {
                int kp = q * 4 + r;
                unsigned int h2 = (&hv.x)[r];
                if (kp < 100) {
                    a0 = dot2bf(wr[kp * 2], h2, a0);
                    a1 = dot2bf(wr[kp * 2 + 1], h2, a1);
                } else if (kp < 114) {
                    uint2 wv = *(const uint2*)&lw[(kp - 100) * 1024 + 2 * t];
                    a0 = dot2bf(wv.x, h2, a0);
                    a1 = dot2bf(wv.y, h2, a1);
                } else {
                    a0 = dot2bf(sw[kp - 114].x, h2, a0);
                    a1 = dot2bf(sw[kp - 114].y, h2, a1);
                }
            }
        }
        a0 += bfbits2f((unsigned short)(xv & 0xffff));
        a1 += bfbits2f((unsigned short)(xv >> 16));

        *(float2*)&gsh[2 * t] = make_float2(a0, a1);
        __syncthreads();

        if (t < 256) {
            float gi = gsh[t], gf = gsh[256 + t], gg = gsh[512 + t], go = gsh[768 + t];
            float si = 1.f / (1.f + expf(-gi));
            float sf = 1.f / (1.f + expf(-gf));
            float so = 1.f / (1.f + expf(-go));
            cst = sf * cst + si * tanhf(gg);
            float h = so * tanhf(cst);
            hb = f2bfbits(h);
            ((unsigned short*)hsb[par ^ 1])[t] = hb;
            oaddr = ((size_t)b * 512 + ts) * 512 + dir * 256 + t;
            have_out = true;
        }
        __syncthreads();
        // out store off the critical path: drains at the NEXT step's barrier
        if (have_out) {
            *(unsigned short*)(out + oaddr) = hb;
            have_out = false;
        }
        par ^= 1;
    }
}

// ---------------------------------------------------------------------------
// V transpose: vt[b][n][s] = v[b][s][n]   (64x64 tiles via LDS)
// ---------------------------------------------------------------------------
__global__ __launch_bounds__(256) void vt_transpose(
    const bf16* __restrict__ v, bf16* __restrict__ vt)
{
    __shared__ unsigned short tile[64 * 73];
    int b = blockIdx.z;
    int s0 = blockIdx.x * 64, n0 = blockIdx.y * 64;
    int tid = threadIdx.x;
    #pragma unroll
    for (int u = 0; u < 2; ++u) {
        int idx = tid + u * 256;
        int si = idx >> 3, nj = (idx & 7) << 3;
        bfrag val = *(const bfrag*)(v + ((size_t)(b * 512 + s0 + si)) * 512 + n0 + nj);
        #pragma unroll
        for (int jj = 0; jj < 8; ++jj)
            tile[(nj + jj) * 73 + si] = ((unsigned short*)&val)[jj];
    }
    __syncthreads();
    #pragma unroll
    for (int u = 0; u < 2; ++u) {
        int idx = tid + u * 256;
        int ni = idx >> 3, sj = (idx & 7) << 3;
        unsigned short outv[8];
        #pragma unroll
        for (int jj = 0; jj < 8; ++jj)
            outv[jj] = tile[ni * 73 + sj + jj];
        *(float4*)(vt + (size_t)b * 262144 + (size_t)(n0 + ni) * 512 + s0 + sj) =
            *(float4*)outv;
    }
}

// ---------------------------------------------------------------------------
// MFMA attention (round-7 verified).
// ---------------------------------------------------------------------------
__global__ __launch_bounds__(256, 2) void attention_mfma(
    const bf16* __restrict__ q, const bf16* __restrict__ k,
    const bf16* __restrict__ vt, bf16* r)
{
    int b = blockIdx.y;
    int s0 = blockIdx.x * 32;
    int tid = threadIdx.x;
    int wave = tid >> 6;
    int sw = wave & 1, dh = wave >> 1;
    int lane = tid & 63;
    int L15 = lane & 15, quad = lane >> 4;

    const bf16* qrow = q + ((size_t)(b * 512 + s0 + sw * 16 + L15)) * 512;
    bfrag qf[8][2];
    #pragma unroll
    for (int h = 0; h < 8; ++h) {
        qf[h][0] = *(const bfrag*)(qrow + h * 64 + quad * 8);
        qf[h][1] = *(const bfrag*)(qrow + h * 64 + 32 + quad * 8);
    }

    f32x4 ctxa[8][2];
    #pragma unroll
    for (int h = 0; h < 8; ++h) {
        ctxa[h][0] = (f32x4)(0.f);
        ctxa[h][1] = (f32x4)(0.f);
    }

    int tperm = ((L15 >> 2) << 3) + (L15 & 3);
    const bf16* kbase = k + (size_t)(b * 512) * 512;
    const bf16* vbase = vt + (size_t)b * 262144;

    for (int tc = 0; tc < 512; tc += 32) {
        f32x4 sa[8][2];
        #pragma unroll
        for (int h = 0; h < 8; ++h) {
            #pragma unroll
            for (int tile = 0; tile < 2; ++tile) {
                const bf16* krow = kbase
                    + (size_t)(tc + tile * 4 + tperm) * 512 + h * 64 + quad * 8;
                bfrag a0 = *(const bfrag*)(krow);
                bfrag a1 = *(const bfrag*)(krow + 32);
                f32x4 acc = __builtin_amdgcn_mfma_f32_16x16x32_bf16(
                    a0, qf[h][0], (f32x4)(0.f), 0, 0, 0);
                acc = __builtin_amdgcn_mfma_f32_16x16x32_bf16(
                    a1, qf[h][1], acc, 0, 0, 0);
                sa[h][tile] = acc;
            }
        }
        bfrag pf[8];
        #pragma unroll
        for (int tile = 0; tile < 2; ++tile) {
            #pragma unroll
            for (int rr = 0; rr < 4; ++rr) {
                float sc[8];
                float m = -1e30f;
                #pragma unroll
                for (int h = 0; h < 8; ++h) {
                    sc[h] = sa[h][tile][rr] * 0.125f;
                    m = fmaxf(m, sc[h]);
                }
                float sum = 0.f;
                #pragma unroll
                for (int h = 0; h < 8; ++h) sum += expf(sc[h] - m);
                float lse = m + logf(sum);
                #pragma unroll
                for (int h = 0; h < 8; ++h)
                    ((unsigned short*)&pf[h])[tile * 4 + rr] = f2bfbits(sc[h] - lse);
            }
        }
        #pragma unroll
        for (int h = 0; h < 8; ++h) {
            #pragma unroll
            for (int dt = 0; dt < 2; ++dt) {
                int n = h * 64 + dh * 32 + dt * 16 + L15;
                bfrag vf = *(const bfrag*)(vbase + (size_t)n * 512 + tc + quad * 8);
                ctxa[h][dt] = __builtin_amdgcn_mfma_f32_16x16x32_bf16(
                    pf[h], vf, ctxa[h][dt], 0, 0, 0);
            }
        }
    }
    #pragma unroll
    for (int h = 0; h < 8; ++h) {
        #pragma unroll
        for (int dt = 0; dt < 2; ++dt) {
            int n = h * 64 + dh * 32 + dt * 16 + L15;
            #pragma unroll
            for (int rr = 0; rr < 4; ++rr) {
                size_t addr =
                    ((size_t)(b * 512 + s0 + sw * 16 + quad * 4 + rr)) * 512 + n;
                float o = __bfloat162float(r[addr]);
                r[addr] = __float2bfloat16(o + ctxa[h][dt][rr]);
            }
        }
    }
}

// ---------------------------------------------------------------------------
// LayerNorm(last dim) -> mean over S -> fc.  One block per (b, s) row.
// ---------------------------------------------------------------------------
__device__ __forceinline__ float block_sum(float val, float* red, int tid)
{
    #pragma unroll
    for (int o = 32; o > 0; o >>= 1) val += __shfl_down(val, o);
    __syncthreads();
    if ((tid & 63) == 0) red[tid >> 6] = val;
    __syncthreads();
    return red[0] + red[1] + red[2] + red[3];
}

__global__ __launch_bounds__(256) void ln_pool_fc(
    const bf16* __restrict__ r, const float* __restrict__ g, const float* __restrict__ bt,
    const float* __restrict__ fcw, const float* __restrict__ fcb, float* __restrict__ out)
{
    __shared__ float red[4];
    int b = blockIdx.y, s = blockIdx.x, tid = threadIdx.x;
    const bf16* row = r + ((size_t)(b * 512 + s)) * 512;
    __hip_bfloat162 rv = *(const __hip_bfloat162*)(row + tid * 2);
    float v0 = __bfloat162float(rv.x), v1 = __bfloat162float(rv.y);
    float tot = block_sum(v0 + v1, red, tid);
    float mu = tot * (1.f / 512.f);
    float d0 = v0 - mu, d1 = v1 - mu;
    float sq = block_sum(d0 * d0 + d1 * d1, red, tid);
    float rs = rsqrtf(sq * (1.f / 512.f) + 1e-5f);
    int n0 = tid * 2;
    float term = d0 * rs * g[n0] * fcw[n0] + d1 * rs * g[n0 + 1] * fcw[n0 + 1];
    if (s == 0) term += 512.f * (bt[n0] * fcw[n0] + bt[n0 + 1] * fcw[n0 + 1]);
    float D = block_sum(term, red, tid);
    if (tid == 0) {
        float val = D * (1.f / 512.f);
        if (s == 0) val += fcb[0];
        atomicAdd(out + b, val);
    }
}

// ---------------------------------------------------------------------------
// Workspace layout (< 200 MiB):
//   [0,64M)        xgf bf16            -> later q,k
//   [64,128M)      xgb bf16            -> later v
//   [128,160M)     out0 bf16           -> later vt (V transposed)
//   [160,192M)     out1 bf16 (attention in-place)
//   [192,194M)     h0 bf16
//   [194,196M)     wl0/wl1 (4 contiguous sets x 131,072 dwords)
// ---------------------------------------------------------------------------
extern "C" void kernel_launch(void* const* d_in, const int* in_sizes, int n_in,
                              void* d_out, int out_size, void* d_ws, size_t ws_size,
                              hipStream_t stream)
{
    (void)in_sizes; (void)n_in; (void)ws_size;
    const float* x      = (const float*)d_in[0];
    const float* conv_w = (const float*)d_in[1];
    const float* conv_b = (const float*)d_in[2];
    const float* bn_g   = (const float*)d_in[3];
    const float* bn_b   = (const float*)d_in[4];
    const float* bn_m   = (const float*)d_in[5];
    const float* bn_v   = (const float*)d_in[6];
    const float* W_ih0f = (const float*)d_in[7];
    const float* W_hh0f = (const float*)d_in[8];
    const float* b0f    = (const float*)d_in[9];
    const float* W_ih0b = (const float*)d_in[10];
    const float* W_hh0b = (const float*)d_in[11];
    const float* b0b    = (const float*)d_in[12];
    const float* W_ih1f = (const float*)d_in[13];
    const float* W_hh1f = (const float*)d_in[14];
    const float* b1f    = (const float*)d_in[15];
    const float* W_ih1b = (const float*)d_in[16];
    const float* W_hh1b = (const float*)d_in[17];
    const float* b1b    = (const float*)d_in[18];
    const float* Wq = (const float*)d_in[19];
    const float* bq = (const float*)d_in[20];
    const float* Wk = (const float*)d_in[21];
    const float* bk = (const float*)d_in[22];
    const float* Wv = (const float*)d_in[23];
    const float* bv = (const float*)d_in[24];
    const float* ln_g = (const float*)d_in[25];
    const float* ln_b = (const float*)d_in[26];
    const float* fc_w = (const float*)d_in[27];
    const float* fc_b = (const float*)d_in[28];
    float* out = (float*)d_out;

    char* ws = (char*)d_ws;
    bf16* xgf  = (bf16*)ws;                               // 33,554,432
    bf16* xgb  = xgf + 33554432;                          // 33,554,432
    bf16* out0 = (bf16*)(ws + 134217728);                 // 16,777,216
    bf16* out1 = (bf16*)(ws + 167772160);                 // 16,777,216
    bf16* h0   = (bf16*)(ws + 201326592);                 // 1,048,576
    unsigned int* wl0 = (unsigned int*)(ws + 203423744);  // 262,144 dwords
    unsigned int* wl1 = wl0 + 262144;                     // 262,144 dwords
    // q,k,v alias the (dead after lstm1) xg region; vt aliases dead out0
    bf16* qb = xgf;
    bf16* kb = xgf + 16777216;
    bf16* vb = xgb;
    bf16* vtb = out0;

    hipMemsetAsync(d_out, 0, (size_t)out_size * sizeof(float), stream);

    pack_lstm4<<<dim3(512, 4), 256, 0, stream>>>(
        W_hh0f, W_hh0b, W_hh1f, W_hh1b, wl0);

    conv_bn_pool<<<dim3(64, 64), 256, 0, stream>>>(
        x, conv_w, conv_b, bn_g, bn_b, bn_m, bn_v, h0);

    // layer-0 input projections (K=32), fwd+bwd in one launch
    gemm_mfma<<<dim3(8, 256, 2), 256, 0, stream>>>(
        h0, W_ih0f, W_ih0b, nullptr, b0f, b0b, nullptr, xgf, xgb, nullptr,
        32768, 1024, 32);

    lstm_reg<<<128, 512, 0, stream>>>(xgf, xgb, wl0, out0);

    // layer-1 input projections (K=512)
    gemm_mfma<<<dim3(8, 256, 2), 256, 0, stream>>>(
        out0, W_ih1f, W_ih1b, nullptr, b1f, b1b, nullptr, xgf, xgb, nullptr,
        32768, 1024, 512);

    lstm_reg<<<128, 512, 0, stream>>>(xgf, xgb, wl1, out1);

    // QKV projections (N=512), 3-way
    gemm_mfma<<<dim3(4, 256, 3), 256, 0, stream>>>(
        out1, Wq, Wk, Wv, bq, bk, bv, qb, kb, vb,
        32768, 512, 512);

    vt_transpose<<<dim3(8, 8, 64), 256, 0, stream>>>(vb, vtb);

    attention_mfma<<<dim3(16, 64), 256, 0, stream>>>(qb, kb, vtb, out1);

    ln_pool_fc<<<dim3(512, 64), 256, 0, stream>>>(out1, ln_g, ln_b, fc_w, fc_b, out);
}